// Round 1
// 133.580 us; speedup vs baseline: 1.0849x; 1.0849x over previous
//
#include <hip/hip_runtime.h>

#define B_TOTAL 16384
#define F_DIM 512
#define H_DIM 256
#define E_NUM 8
#define OUT_COLS 32
#define DA 8
#define TM 32                 // samples per block
#define HSTRIDE (H_DIM + 8)   // 264 halves: rows 16B-aligned, bank-stride 4
#define XSTRIDE (F_DIM + 8)   // 520 halves: same bank-stride-4 pattern
#define MLP_BLOCKS ((B_TOTAL + E_NUM * (TM - 1) + TM - 1) / TM)  // 520

typedef __attribute__((ext_vector_type(8))) _Float16 half8;
typedef __attribute__((ext_vector_type(4))) _Float16 half4;
typedef __attribute__((ext_vector_type(4))) float float4v;

// ---------------- bucket samples by expert (block-aggregated atomics) ----------------
__global__ void k_bucket(const int* __restrict__ act, int* __restrict__ counts,
                         int* __restrict__ idxbuf) {
  __shared__ int wcnt[4][E_NUM];
  __shared__ int wbase[4][E_NUM];
  int t = threadIdx.x;
  int lane = t & 63, wave = t >> 6;
  int b = blockIdx.x * 256 + t;
  int e = act[b] & 7;

  unsigned long long mymask = 0;
#pragma unroll
  for (int v = 0; v < E_NUM; ++v) {
    unsigned long long m = __ballot(e == v);
    if (lane == 0) wcnt[wave][v] = (int)__popcll(m);
    if (e == v) mymask = m;
  }
  int rank = (int)__popcll(mymask & ((1ull << lane) - 1ull));
  __syncthreads();
  if (t < E_NUM) {
    int c0 = wcnt[0][t], c1 = wcnt[1][t], c2 = wcnt[2][t], c3 = wcnt[3][t];
    int base = atomicAdd(&counts[t], c0 + c1 + c2 + c3);
    wbase[0][t] = base;
    wbase[1][t] = base + c0;
    wbase[2][t] = base + c0 + c1;
    wbase[3][t] = base + c0 + c1 + c2;
  }
  __syncthreads();
  idxbuf[e * B_TOTAL + wbase[wave][e] + rank] = b;
}

// ---------------- fused weight prep: transpose W1,W2 (fp32->fp16) + W3 pack ----------------
// Also zeroes counts (this kernel is launched BEFORE k_bucket).
__global__ void k_prep(const float* __restrict__ W1, const float* __restrict__ W2,
                       const float* __restrict__ W3,
                       _Float16* __restrict__ W1t, _Float16* __restrict__ W2t,
                       _Float16* __restrict__ W3t, int* __restrict__ counts) {
  if (blockIdx.x == 0 && threadIdx.x < E_NUM) counts[threadIdx.x] = 0;

  __shared__ float tile[32][33];
  int bid = blockIdx.x;
  int tx = threadIdx.x & 31, ty = threadIdx.x >> 5;  // 32x8

  const float* S; _Float16* D; int K, N, k0, n0;
  if (bid < 1024) {            // W1: (512,256) -> (256,512), 128 tiles/expert
    int e = bid >> 7, tt = bid & 127;
    K = F_DIM; N = H_DIM; k0 = (tt >> 3) * 32; n0 = (tt & 7) * 32;
    S = W1 + (size_t)e * F_DIM * H_DIM;
    D = W1t + (size_t)e * H_DIM * F_DIM;
  } else if (bid < 1536) {     // W2: (256,256) -> (256,256), 64 tiles/expert
    int r = bid - 1024;
    int e = r >> 6, tt = r & 63;
    K = H_DIM; N = H_DIM; k0 = (tt >> 3) * 32; n0 = (tt & 7) * 32;
    S = W2 + (size_t)e * H_DIM * H_DIM;
    D = W2t + (size_t)e * H_DIM * H_DIM;
  } else {                     // W3: (256,32) -> (16,256) with rows 8..15 = 0
    int e = bid - 1536;
    int k = threadIdx.x;
#pragma unroll
    for (int o = 0; o < 16; ++o) {
      float v = (o < DA) ? W3[((size_t)e * H_DIM + k) * OUT_COLS + o] : 0.f;
      W3t[((size_t)e * 16 + o) * H_DIM + k] = (_Float16)v;
    }
    return;
  }
#pragma unroll
  for (int r = 0; r < 32; r += 8)
    tile[ty + r][tx] = S[(size_t)(k0 + ty + r) * N + (n0 + tx)];
  __syncthreads();
#pragma unroll
  for (int r = 0; r < 32; r += 8)
    D[(size_t)(n0 + ty + r) * K + (k0 + tx)] = (_Float16)tile[tx][ty + r];
}

// ---------------- fused gather + 3-layer expert MLP ----------------
// 1-D grid over compact slots (every block does work). Per block: stage 32 X rows
// fp32->fp16 into LDS via idxbuf, then 3 MFMA layers. Weight A-operands use a
// depth-4 modulo register pipeline (~L2 latency of issue distance); B-operands
// come from LDS. H2 aliases the X staging buffer (dead after layer 1).
__global__ __launch_bounds__(256, 3) void k_mlp(
    const float* __restrict__ X,
    const _Float16* __restrict__ W1t,
    const _Float16* __restrict__ W2t,
    const _Float16* __restrict__ W3t,
    const float* __restrict__ b1,
    const float* __restrict__ b2,
    const float* __restrict__ b3,
    const int* __restrict__ counts,
    const int* __restrict__ idxbuf,
    float* __restrict__ out)
{
  __shared__ _Float16 Xs[TM][XSTRIDE];   // 33280 B; reused as H2 after layer 1
  __shared__ _Float16 H1s[TM][HSTRIDE];  // 16896 B
  _Float16 (*H2s)[HSTRIDE] = reinterpret_cast<_Float16(*)[HSTRIDE]>(&Xs[0][0]);

  int t = threadIdx.x;
  int lane = t & 63;
  int wave = t >> 6;
  int quad = lane >> 4;
  int l16 = lane & 15;
  int hbase = wave * 64;
  int kq = quad * 8;

  // --- map block -> (expert, tile0) over 32-rounded compact regions ---
  int slot0 = blockIdx.x * TM;
  int base = 0, e = 0, tile0 = -1, cnt = 0;
#pragma unroll
  for (int j = 0; j < E_NUM; ++j) {
    int c = counts[j];
    int rc = (c + 31) & ~31;
    if (tile0 < 0) {
      if (slot0 < base + rc) { e = j; tile0 = slot0 - base; cnt = c; }
      else base += rc;
    }
  }
  if (tile0 < 0) return;

  const float4v vzero = {0.f, 0.f, 0.f, 0.f};

  // --- issue layer-1 weight prefetch FIRST (in flight during X staging) ---
  const _Float16* wb = W1t + ((size_t)e * H_DIM + hbase + l16) * F_DIM + kq;
  half8 a_p[4][4];
#pragma unroll
  for (int p = 0; p < 4; ++p)
#pragma unroll
    for (int mt = 0; mt < 4; ++mt)
      a_p[p][mt] = *(const half8*)(wb + (size_t)mt * 16 * F_DIM + p * 32);

  // --- stage X tile: fp32 gather -> fp16 LDS (8 threads per row) ---
  {
    int s = t >> 3, sub = t & 7;
    int si = tile0 + s;
    bool valid = (si < cnt);
    int row = valid ? idxbuf[e * B_TOTAL + si] : 0;
    const float* src = X + (size_t)row * F_DIM;
#pragma unroll
    for (int i = 0; i < 16; ++i) {
      int c = sub * 4 + i * 32;
      half4 h;
      if (valid) {
        float4v v = *(const float4v*)(src + c);
        h[0] = (_Float16)v.x; h[1] = (_Float16)v.y;
        h[2] = (_Float16)v.z; h[3] = (_Float16)v.w;
      } else {
        h[0] = (_Float16)0.f; h[1] = (_Float16)0.f;
        h[2] = (_Float16)0.f; h[3] = (_Float16)0.f;
      }
      *(half4*)&Xs[s][c] = h;
    }
  }
  __syncthreads();

  float4v acc[4][2];
#pragma unroll
  for (int mt = 0; mt < 4; ++mt)
#pragma unroll
    for (int st = 0; st < 2; ++st) acc[mt][st] = vzero;

  // ======== Layer 1: H1^T[h][s] = sum_k W1t[h][k] * Xs[s][k] ========
#pragma unroll
  for (int kb = 0; kb < F_DIM; kb += 32) {
    int p = (kb >> 5) & 3;
    half8 a_cur[4];
#pragma unroll
    for (int mt = 0; mt < 4; ++mt) a_cur[mt] = a_p[p][mt];
    if (kb + 128 < F_DIM) {
#pragma unroll
      for (int mt = 0; mt < 4; ++mt)
        a_p[p][mt] = *(const half8*)(wb + (size_t)mt * 16 * F_DIM + kb + 128);
    }
    half8 b_cur[2];
#pragma unroll
    for (int st = 0; st < 2; ++st)
      b_cur[st] = *(const half8*)&Xs[st * 16 + l16][kb + kq];
#pragma unroll
    for (int mt = 0; mt < 4; ++mt)
#pragma unroll
      for (int st = 0; st < 2; ++st)
        acc[mt][st] = __builtin_amdgcn_mfma_f32_16x16x32_f16(a_cur[mt], b_cur[st], acc[mt][st], 0, 0, 0);
  }

  // --- issue layer-2 weight prefetch before epilogue+barrier (overlaps drain) ---
  const _Float16* wb2 = W2t + ((size_t)e * H_DIM + hbase + l16) * H_DIM + kq;
#pragma unroll
  for (int p = 0; p < 4; ++p)
#pragma unroll
    for (int mt = 0; mt < 4; ++mt)
      a_p[p][mt] = *(const half8*)(wb2 + (size_t)mt * 16 * H_DIM + p * 32);

  // layer-1 epilogue: bias + relu -> H1s[sample][hidden]
#pragma unroll
  for (int mt = 0; mt < 4; ++mt) {
    int h0 = hbase + mt * 16 + quad * 4;
    float4v bb = *(const float4v*)&b1[e * H_DIM + h0];
#pragma unroll
    for (int st = 0; st < 2; ++st) {
      half4 hv;
#pragma unroll
      for (int r = 0; r < 4; ++r) {
        float v = acc[mt][st][r] + bb[r];
        hv[r] = (_Float16)(v > 0.f ? v : 0.f);
      }
      *(half4*)&H1s[st * 16 + l16][h0] = hv;
    }
  }
  __syncthreads();

  // ======== Layer 2: H2^T[h][s] = sum_k W2t[h][k] * H1[s][k] ========
#pragma unroll
  for (int mt = 0; mt < 4; ++mt)
#pragma unroll
    for (int st = 0; st < 2; ++st) acc[mt][st] = vzero;

#pragma unroll
  for (int kb = 0; kb < H_DIM; kb += 32) {
    int p = (kb >> 5) & 3;
    half8 a_cur[4];
#pragma unroll
    for (int mt = 0; mt < 4; ++mt) a_cur[mt] = a_p[p][mt];
    if (kb + 128 < H_DIM) {
#pragma unroll
      for (int mt = 0; mt < 4; ++mt)
        a_p[p][mt] = *(const half8*)(wb2 + (size_t)mt * 16 * H_DIM + kb + 128);
    }
    half8 b_cur[2];
#pragma unroll
    for (int st = 0; st < 2; ++st)
      b_cur[st] = *(const half8*)&H1s[st * 16 + l16][kb + kq];
#pragma unroll
    for (int mt = 0; mt < 4; ++mt)
#pragma unroll
      for (int st = 0; st < 2; ++st)
        acc[mt][st] = __builtin_amdgcn_mfma_f32_16x16x32_f16(a_cur[mt], b_cur[st], acc[mt][st], 0, 0, 0);
  }

  // layer-2 epilogue -> H2s (aliases Xs; all Xs reads completed before 1st barrier)
#pragma unroll
  for (int mt = 0; mt < 4; ++mt) {
    int h0 = hbase + mt * 16 + quad * 4;
    float4v bb = *(const float4v*)&b2[e * H_DIM + h0];
#pragma unroll
    for (int st = 0; st < 2; ++st) {
      half4 hv;
#pragma unroll
      for (int r = 0; r < 4; ++r) {
        float v = acc[mt][st][r] + bb[r];
        hv[r] = (_Float16)(v > 0.f ? v : 0.f);
      }
      *(half4*)&H2s[st * 16 + l16][h0] = hv;
    }
  }
  __syncthreads();

  // ======== Layer 3: waves 0,1 each compute one 16-sample out tile ========
  if (wave < 2) {
    const _Float16* wb3 = W3t + ((size_t)e * 16 + l16) * H_DIM + kq;
    half8 af[8];
#pragma unroll
    for (int i = 0; i < 8; ++i) af[i] = *(const half8*)(wb3 + i * 32);
    float4v acc3 = vzero;
#pragma unroll
    for (int i = 0; i < 8; ++i) {
      half8 bfrag = *(const half8*)&H2s[wave * 16 + l16][i * 32 + kq];
      acc3 = __builtin_amdgcn_mfma_f32_16x16x32_f16(af[i], bfrag, acc3, 0, 0, 0);
    }
    int si = tile0 + wave * 16 + l16;
    if (quad < 2 && si < cnt) {
      int row = idxbuf[e * B_TOTAL + si];
      float4v bb = *(const float4v*)&b3[e * OUT_COLS + quad * 4];
      float4v y;
#pragma unroll
      for (int r = 0; r < 4; ++r) y[r] = acc3[r] + bb[r];
      *(float4v*)&out[(size_t)row * DA + quad * 4] = y;
    }
  }
}

extern "C" void kernel_launch(void* const* d_in, const int* in_sizes, int n_in,
                              void* d_out, int out_size, void* d_ws, size_t ws_size,
                              hipStream_t stream) {
  const float* features = (const float*)d_in[0];
  const float* W1 = (const float*)d_in[1];
  const float* b1 = (const float*)d_in[2];
  const float* W2 = (const float*)d_in[3];
  const float* b2 = (const float*)d_in[4];
  const float* W3 = (const float*)d_in[5];
  const float* b3 = (const float*)d_in[6];
  const int* act = (const int*)d_in[7];
  float* out = (float*)d_out;

  char* ws = (char*)d_ws;
  int* counts = (int*)ws;                                      // 256 B
  int* idxbuf = (int*)(ws + 256);                              // 512 KiB
  _Float16* W1t = (_Float16*)(ws + 256 + 524288);              // 2 MiB
  _Float16* W2t = (_Float16*)(ws + 256 + 524288 + 2097152);    // 1 MiB
  _Float16* W3t = (_Float16*)(ws + 256 + 524288 + 2097152 + 1048576);  // 64 KiB

  // prep zeroes counts (runs before bucket); 3 dispatches total
  k_prep<<<1544, 256, 0, stream>>>(W1, W2, W3, W1t, W2t, W3t, counts);
  k_bucket<<<B_TOTAL / 256, 256, 0, stream>>>(act, counts, idxbuf);
  k_mlp<<<MLP_BLOCKS, 256, 0, stream>>>(features, W1t, W2t, W3t,
                                        b1, b2, b3, counts, idxbuf, out);
}

// Round 2
// 127.175 us; speedup vs baseline: 1.1395x; 1.0504x over previous
//
#include <hip/hip_runtime.h>

#define B_TOTAL 16384
#define F_DIM 512
#define H_DIM 256
#define E_NUM 8
#define OUT_COLS 32
#define DA 8
#define TM 32                 // samples per block
#define HSTRIDE (H_DIM + 8)   // 264 halves: rows 16B-aligned, bank-stride 4
#define MLP_BLOCKS ((B_TOTAL + E_NUM * (TM - 1) + TM - 1) / TM)  // 520
#define PREP_BLOCKS 1544
#define BUCKET_BLOCKS (B_TOTAL / 256)

typedef __attribute__((ext_vector_type(8))) _Float16 half8;
typedef __attribute__((ext_vector_type(4))) _Float16 half4;
typedef __attribute__((ext_vector_type(4))) float float4v;

// ---------------- merged setup: weight prep (blocks 0..1543) + bucket (1544..1607) ----
// The two halves are independent; merging overlaps their latency in one dispatch.
__global__ void k_setup(const float* __restrict__ W1, const float* __restrict__ W2,
                        const float* __restrict__ W3,
                        _Float16* __restrict__ W1t, _Float16* __restrict__ W2t,
                        _Float16* __restrict__ W3t,
                        const int* __restrict__ act, int* __restrict__ counts,
                        int* __restrict__ idxbuf) {
  int bid = blockIdx.x;
  if (bid >= PREP_BLOCKS) {
    // ---- bucket samples by expert (block-aggregated atomics) ----
    __shared__ int wcnt[4][E_NUM];
    __shared__ int wbase[4][E_NUM];
    int t = threadIdx.x;
    int lane = t & 63, wave = t >> 6;
    int b = (bid - PREP_BLOCKS) * 256 + t;
    int e = act[b] & 7;

    unsigned long long mymask = 0;
#pragma unroll
    for (int v = 0; v < E_NUM; ++v) {
      unsigned long long m = __ballot(e == v);
      if (lane == 0) wcnt[wave][v] = (int)__popcll(m);
      if (e == v) mymask = m;
    }
    int rank = (int)__popcll(mymask & ((1ull << lane) - 1ull));
    __syncthreads();
    if (t < E_NUM) {
      int c0 = wcnt[0][t], c1 = wcnt[1][t], c2 = wcnt[2][t], c3 = wcnt[3][t];
      int base = atomicAdd(&counts[t], c0 + c1 + c2 + c3);
      wbase[0][t] = base;
      wbase[1][t] = base + c0;
      wbase[2][t] = base + c0 + c1;
      wbase[3][t] = base + c0 + c1 + c2;
    }
    __syncthreads();
    idxbuf[e * B_TOTAL + wbase[wave][e] + rank] = b;
    return;
  }

  // ---- weight prep: transpose W1,W2 (fp32->fp16) + W3 pack ----
  __shared__ float tile[32][33];
  int tx = threadIdx.x & 31, ty = threadIdx.x >> 5;  // 32x8

  const float* S; _Float16* D; int K, N, k0, n0;
  if (bid < 1024) {            // W1: (512,256) -> (256,512), 128 tiles/expert
    int e = bid >> 7, tt = bid & 127;
    K = F_DIM; N = H_DIM; k0 = (tt >> 3) * 32; n0 = (tt & 7) * 32;
    S = W1 + (size_t)e * F_DIM * H_DIM;
    D = W1t + (size_t)e * H_DIM * F_DIM;
  } else if (bid < 1536) {     // W2: (256,256) -> (256,256), 64 tiles/expert
    int r = bid - 1024;
    int e = r >> 6, tt = r & 63;
    K = H_DIM; N = H_DIM; k0 = (tt >> 3) * 32; n0 = (tt & 7) * 32;
    S = W2 + (size_t)e * H_DIM * H_DIM;
    D = W2t + (size_t)e * H_DIM * H_DIM;
  } else {                     // W3: (256,32) -> (16,256) with rows 8..15 = 0
    int e = bid - 1536;
    int k = threadIdx.x;
#pragma unroll
    for (int o = 0; o < 16; ++o) {
      float v = (o < DA) ? W3[((size_t)e * H_DIM + k) * OUT_COLS + o] : 0.f;
      W3t[((size_t)e * 16 + o) * H_DIM + k] = (_Float16)v;
    }
    return;
  }
#pragma unroll
  for (int r = 0; r < 32; r += 8)
    tile[ty + r][tx] = S[(size_t)(k0 + ty + r) * N + (n0 + tx)];
  __syncthreads();
#pragma unroll
  for (int r = 0; r < 32; r += 8)
    D[(size_t)(n0 + ty + r) * K + (k0 + tx)] = (_Float16)tile[tx][ty + r];
}

// ---------------- fused gather + 3-layer expert MLP ----------------
// 520 blocks x 8 waves (512 thr) = 4160 waves -> ~4 waves/SIMD for latency hiding.
// Wave owns 32 hidden rows (2 m-tiles x 2 s-tiles). LDS = 2 x [32][264] fp16 (34 KB):
//   bufA: X cols 0..255   -> later H2      bufB: X cols 256..511 -> later H1
// X chunk1 staged via async-split: loads issued before barrier, LDS-written after
// the first half of the layer-1 K-loop (HBM latency hides under MFMA).
// Weight A-operands: depth-3 modulo register pipeline from L2.
__global__ __launch_bounds__(512, 4) void k_mlp(
    const float* __restrict__ X,
    const _Float16* __restrict__ W1t,
    const _Float16* __restrict__ W2t,
    const _Float16* __restrict__ W3t,
    const float* __restrict__ b1,
    const float* __restrict__ b2,
    const float* __restrict__ b3,
    const int* __restrict__ counts,
    const int* __restrict__ idxbuf,
    float* __restrict__ out)
{
  __shared__ _Float16 bufA[TM][HSTRIDE];  // 16896 B
  __shared__ _Float16 bufB[TM][HSTRIDE];  // 16896 B

  int t = threadIdx.x;
  int lane = t & 63;
  int wave = t >> 6;          // 0..7
  int quad = lane >> 4;
  int l16 = lane & 15;
  int hbase = wave * 32;      // 32 hidden rows per wave
  int kq = quad * 8;

  // --- map block -> (expert, tile0) over 32-rounded compact regions ---
  int slot0 = blockIdx.x * TM;
  int base = 0, e = 0, tile0 = -1, cnt = 0;
#pragma unroll
  for (int j = 0; j < E_NUM; ++j) {
    int c = counts[j];
    int rc = (c + 31) & ~31;
    if (tile0 < 0) {
      if (slot0 < base + rc) { e = j; tile0 = slot0 - base; cnt = c; }
      else base += rc;
    }
  }
  if (tile0 < 0) return;

  const float4v vzero = {0.f, 0.f, 0.f, 0.f};

  // --- stage X: 16 threads per sample row; chunk0 -> bufA now, chunk1 held in regs ---
  int s = t >> 4, sub = t & 15;
  int si_st = tile0 + s;
  bool valid = (si_st < cnt);
  int xrow = valid ? idxbuf[e * B_TOTAL + si_st] : 0;
  const float* src = X + (size_t)xrow * F_DIM;

  float4v c1reg[4];  // chunk1 (cols 256..511) in-flight registers
#pragma unroll
  for (int i = 0; i < 4; ++i) {
    int c = sub * 4 + i * 64;
    c1reg[i] = valid ? *(const float4v*)(src + 256 + c) : vzero;
  }
#pragma unroll
  for (int i = 0; i < 4; ++i) {
    int c = sub * 4 + i * 64;
    float4v v = valid ? *(const float4v*)(src + c) : vzero;
    half4 h;
    h[0] = (_Float16)v.x; h[1] = (_Float16)v.y;
    h[2] = (_Float16)v.z; h[3] = (_Float16)v.w;
    *(half4*)&bufA[s][c] = h;
  }

  // --- layer-1 weight prefetch (depth-3 modulo pipeline, 2 m-tiles) ---
  const _Float16* wb = W1t + ((size_t)e * H_DIM + hbase + l16) * F_DIM + kq;
  half8 a_p[3][2];
#pragma unroll
  for (int p = 0; p < 3; ++p)
#pragma unroll
    for (int mt = 0; mt < 2; ++mt)
      a_p[p][mt] = *(const half8*)(wb + (size_t)mt * 16 * F_DIM + p * 32);

  __syncthreads();

  float4v acc[2][2];
#pragma unroll
  for (int mt = 0; mt < 2; ++mt)
#pragma unroll
    for (int st = 0; st < 2; ++st) acc[mt][st] = vzero;

  // ======== Layer 1a: kb 0..255 from bufA (chunk1 loads still in flight) ========
#pragma unroll
  for (int kb = 0; kb < 256; kb += 32) {
    int p = (kb >> 5) % 3;
    half8 a_cur[2];
#pragma unroll
    for (int mt = 0; mt < 2; ++mt) a_cur[mt] = a_p[p][mt];
#pragma unroll
    for (int mt = 0; mt < 2; ++mt)
      a_p[p][mt] = *(const half8*)(wb + (size_t)mt * 16 * F_DIM + kb + 96);
    half8 b_cur[2];
#pragma unroll
    for (int st = 0; st < 2; ++st)
      b_cur[st] = *(const half8*)&bufA[st * 16 + l16][kb + kq];
#pragma unroll
    for (int mt = 0; mt < 2; ++mt)
#pragma unroll
      for (int st = 0; st < 2; ++st)
        acc[mt][st] = __builtin_amdgcn_mfma_f32_16x16x32_f16(a_cur[mt], b_cur[st], acc[mt][st], 0, 0, 0);
  }

  // --- land chunk1 into bufB (loads have been hiding under layer 1a) ---
#pragma unroll
  for (int i = 0; i < 4; ++i) {
    int c = sub * 4 + i * 64;
    half4 h;
    h[0] = (_Float16)c1reg[i].x; h[1] = (_Float16)c1reg[i].y;
    h[2] = (_Float16)c1reg[i].z; h[3] = (_Float16)c1reg[i].w;
    *(half4*)&bufB[s][c] = h;
  }
  __syncthreads();

  // ======== Layer 1b: kb 256..511 from bufB ========
#pragma unroll
  for (int kb = 256; kb < F_DIM; kb += 32) {
    int p = (kb >> 5) % 3;
    half8 a_cur[2];
#pragma unroll
    for (int mt = 0; mt < 2; ++mt) a_cur[mt] = a_p[p][mt];
    if (kb + 96 < F_DIM) {
#pragma unroll
      for (int mt = 0; mt < 2; ++mt)
        a_p[p][mt] = *(const half8*)(wb + (size_t)mt * 16 * F_DIM + kb + 96);
    }
    half8 b_cur[2];
#pragma unroll
    for (int st = 0; st < 2; ++st)
      b_cur[st] = *(const half8*)&bufB[st * 16 + l16][kb - 256 + kq];
#pragma unroll
    for (int mt = 0; mt < 2; ++mt)
#pragma unroll
      for (int st = 0; st < 2; ++st)
        acc[mt][st] = __builtin_amdgcn_mfma_f32_16x16x32_f16(a_cur[mt], b_cur[st], acc[mt][st], 0, 0, 0);
  }

  // --- issue layer-2 weight prefetch before barrier (overlaps epilogue) ---
  const _Float16* wb2 = W2t + ((size_t)e * H_DIM + hbase + l16) * H_DIM + kq;
#pragma unroll
  for (int p = 0; p < 3; ++p)
#pragma unroll
    for (int mt = 0; mt < 2; ++mt)
      a_p[p][mt] = *(const half8*)(wb2 + (size_t)mt * 16 * H_DIM + p * 32);

  __syncthreads();  // all waves done reading bufB as X before H1 lands there

  // layer-1 epilogue: bias + relu -> bufB (= H1[sample][hidden])
#pragma unroll
  for (int mt = 0; mt < 2; ++mt) {
    int h0 = hbase + mt * 16 + quad * 4;
    float4v bb = *(const float4v*)&b1[e * H_DIM + h0];
#pragma unroll
    for (int st = 0; st < 2; ++st) {
      half4 hv;
#pragma unroll
      for (int r = 0; r < 4; ++r) {
        float v = acc[mt][st][r] + bb[r];
        hv[r] = (_Float16)(v > 0.f ? v : 0.f);
      }
      *(half4*)&bufB[st * 16 + l16][h0] = hv;
    }
  }
  __syncthreads();

  // ======== Layer 2: H2^T[h][s] = sum_k W2t[h][k] * H1[s][k] ========
#pragma unroll
  for (int mt = 0; mt < 2; ++mt)
#pragma unroll
    for (int st = 0; st < 2; ++st) acc[mt][st] = vzero;

#pragma unroll
  for (int kb = 0; kb < H_DIM; kb += 32) {
    int p = (kb >> 5) % 3;
    half8 a_cur[2];
#pragma unroll
    for (int mt = 0; mt < 2; ++mt) a_cur[mt] = a_p[p][mt];
    if (kb + 96 < H_DIM) {
#pragma unroll
      for (int mt = 0; mt < 2; ++mt)
        a_p[p][mt] = *(const half8*)(wb2 + (size_t)mt * 16 * H_DIM + kb + 96);
    }
    half8 b_cur[2];
#pragma unroll
    for (int st = 0; st < 2; ++st)
      b_cur[st] = *(const half8*)&bufB[st * 16 + l16][kb + kq];
#pragma unroll
    for (int mt = 0; mt < 2; ++mt)
#pragma unroll
      for (int st = 0; st < 2; ++st)
        acc[mt][st] = __builtin_amdgcn_mfma_f32_16x16x32_f16(a_cur[mt], b_cur[st], acc[mt][st], 0, 0, 0);
  }

  // layer-2 epilogue -> bufA (= H2; X chunk0 dead, nobody reads bufA during L2)
#pragma unroll
  for (int mt = 0; mt < 2; ++mt) {
    int h0 = hbase + mt * 16 + quad * 4;
    float4v bb = *(const float4v*)&b2[e * H_DIM + h0];
#pragma unroll
    for (int st = 0; st < 2; ++st) {
      half4 hv;
#pragma unroll
      for (int r = 0; r < 4; ++r) {
        float v = acc[mt][st][r] + bb[r];
        hv[r] = (_Float16)(v > 0.f ? v : 0.f);
      }
      *(half4*)&bufA[st * 16 + l16][h0] = hv;
    }
  }

  // --- waves 0,1: prefetch W3 before the barrier ---
  half8 af[8];
  const _Float16* wb3 = W3t + ((size_t)e * 16 + l16) * H_DIM + kq;
  if (wave < 2) {
#pragma unroll
    for (int i = 0; i < 8; ++i) af[i] = *(const half8*)(wb3 + i * 32);
  }
  __syncthreads();

  // ======== Layer 3: waves 0,1 each compute one 16-sample out tile ========
  if (wave < 2) {
    float4v acc3 = vzero;
#pragma unroll
    for (int i = 0; i < 8; ++i) {
      half8 bfrag = *(const half8*)&bufA[wave * 16 + l16][i * 32 + kq];
      acc3 = __builtin_amdgcn_mfma_f32_16x16x32_f16(af[i], bfrag, acc3, 0, 0, 0);
    }
    int si = tile0 + wave * 16 + l16;
    if (quad < 2 && si < cnt) {
      int row = idxbuf[e * B_TOTAL + si];
      float4v bb = *(const float4v*)&b3[e * OUT_COLS + quad * 4];
      float4v y;
#pragma unroll
      for (int r = 0; r < 4; ++r) y[r] = acc3[r] + bb[r];
      *(float4v*)&out[(size_t)row * DA + quad * 4] = y;
    }
  }
}

extern "C" void kernel_launch(void* const* d_in, const int* in_sizes, int n_in,
                              void* d_out, int out_size, void* d_ws, size_t ws_size,
                              hipStream_t stream) {
  const float* features = (const float*)d_in[0];
  const float* W1 = (const float*)d_in[1];
  const float* b1 = (const float*)d_in[2];
  const float* W2 = (const float*)d_in[3];
  const float* b2 = (const float*)d_in[4];
  const float* W3 = (const float*)d_in[5];
  const float* b3 = (const float*)d_in[6];
  const int* act = (const int*)d_in[7];
  float* out = (float*)d_out;

  char* ws = (char*)d_ws;
  int* counts = (int*)ws;                                      // 256 B
  int* idxbuf = (int*)(ws + 256);                              // 512 KiB
  _Float16* W1t = (_Float16*)(ws + 256 + 524288);              // 2 MiB
  _Float16* W2t = (_Float16*)(ws + 256 + 524288 + 2097152);    // 1 MiB
  _Float16* W3t = (_Float16*)(ws + 256 + 524288 + 2097152 + 1048576);  // 64 KiB

  hipMemsetAsync(counts, 0, 256, stream);
  k_setup<<<PREP_BLOCKS + BUCKET_BLOCKS, 256, 0, stream>>>(W1, W2, W3, W1t, W2t, W3t,
                                                           act, counts, idxbuf);
  k_mlp<<<MLP_BLOCKS, 512, 0, stream>>>(features, W1t, W2t, W3t,
                                        b1, b2, b3, counts, idxbuf, out);
}